// Round 2
// baseline (955.899 us; speedup 1.0000x reference)
//
#include <hip/hip_runtime.h>
#include <stdint.h>
#include <stddef.h>

// ---------------- problem constants (fixed by reference) ----------------
#define BB     4096
#define IN_D   2048
#define OUT_D  2048
#define NGATE  8192   // 4*OUT

static constexpr size_t S_X   = (size_t)BB * IN_D;      // 8388608
static constexpr size_t S_HX  = (size_t)BB * OUT_D;     // 8388608
static constexpr size_t S_CX  = (size_t)BB * OUT_D;     // 8388608
static constexpr size_t S_WIH = (size_t)NGATE * IN_D;   // 16777216
static constexpr size_t S_WHH = (size_t)NGATE * OUT_D;  // 16777216
static constexpr size_t S_WP  = (size_t)OUT_D * OUT_D;  // 4194304

// bf16 scratch region layout (element offsets); dst order == concatenated src order
static constexpr size_t O_X   = 0;
static constexpr size_t O_HX  = O_X   + S_X;
static constexpr size_t O_CX  = O_HX  + S_HX;           // reused later for cy_bf16
static constexpr size_t O_WIH = O_CX  + S_CX;
static constexpr size_t O_WHH = O_WIH + S_WIH;
static constexpr size_t O_WPI = O_WHH + S_WHH;
static constexpr size_t O_WPF = O_WPI + S_WP;
static constexpr size_t O_WPO = O_WPF + S_WP;
static constexpr size_t TOT_BF = O_WPO + S_WP;          // 71303168 elements
static constexpr size_t GATES_OFF = TOT_BF * 2;         // bytes into ws (16B aligned)

using bf16x8 = __attribute__((ext_vector_type(8))) short;  // 8 bf16 in 4 VGPRs
using f32x4  = __attribute__((ext_vector_type(4))) float;  // MFMA accumulator

// ---------------- helpers ----------------
__device__ __forceinline__ unsigned short f2bf(float f) {
  unsigned u = __builtin_bit_cast(unsigned, f);
  u += 0x7FFFu + ((u >> 16) & 1u);   // RNE (inputs are finite)
  return (unsigned short)(u >> 16);
}
__device__ __forceinline__ float sigm(float x)  { return 1.0f / (1.0f + __expf(-x)); }
__device__ __forceinline__ float tanh_(float x) { return 1.0f - 2.0f / (__expf(2.0f * x) + 1.0f); }

__device__ __forceinline__ void gload16(const void* g, void* l) {
  // async global->LDS, 16B per lane; LDS dest = wave-uniform base + lane*16
  __builtin_amdgcn_global_load_lds(
      (const __attribute__((address_space(1))) void*)g,
      (__attribute__((address_space(3))) void*)l,
      16, 0, 0);
}

// ---------------- kernel 1: fp32 -> bf16 conversion ----------------
__global__ void cvt_kernel(const float* __restrict__ x,  const float* __restrict__ hx,
                           const float* __restrict__ cx, const float* __restrict__ wih,
                           const float* __restrict__ whh, const float* __restrict__ wpi,
                           const float* __restrict__ wpf, const float* __restrict__ wpo,
                           unsigned short* __restrict__ dst) {
  const long total4 = (long)(TOT_BF / 4);
  for (long c = (long)blockIdx.x * blockDim.x + threadIdx.x; c < total4;
       c += (long)gridDim.x * blockDim.x) {
    long e0 = c * 4;
    const float* s; long r;
    if      (e0 < (long)O_HX)  { s = x;   r = e0 - (long)O_X;   }
    else if (e0 < (long)O_CX)  { s = hx;  r = e0 - (long)O_HX;  }
    else if (e0 < (long)O_WIH) { s = cx;  r = e0 - (long)O_CX;  }
    else if (e0 < (long)O_WHH) { s = wih; r = e0 - (long)O_WIH; }
    else if (e0 < (long)O_WPI) { s = whh; r = e0 - (long)O_WHH; }
    else if (e0 < (long)O_WPF) { s = wpi; r = e0 - (long)O_WPI; }
    else if (e0 < (long)O_WPO) { s = wpf; r = e0 - (long)O_WPF; }
    else                       { s = wpo; r = e0 - (long)O_WPO; }
    float4 v = *(const float4*)(s + r);
    ushort4 o;
    o.x = f2bf(v.x); o.y = f2bf(v.y); o.z = f2bf(v.z); o.w = f2bf(v.w);
    *(ushort4*)(dst + e0) = o;
  }
}

// ---------------- GEMM core: one K=2048 segment, NT layout ----------------
// C[128,128] (block tile) += A[128 rows, 2048] * B[128 rows, 2048]^T
// 256 threads = 4 waves (2x2), each wave 64x64 via 4x4 frags of 16x16x32 MFMA.
// BK=32, single-buffered LDS, global_load_lds width 16.
__device__ __forceinline__ void kseg2048(const unsigned short* __restrict__ A,
                                         const unsigned short* __restrict__ Bm,
                                         unsigned short* sA, unsigned short* sB,
                                         f32x4 (&acc)[4][4]) {
  const int tid  = threadIdx.x;
  const int lane = tid & 63;
  const int wave = tid >> 6;
  const int wm = (wave >> 1) * 64;
  const int wn = (wave & 1) * 64;

  // staging: chunk c = round*256 + tid covers LDS bytes [c*16, c*16+16)
  // linear row-major [128][32] bf16 tile: row = c>>2, col8 = (c&3)*8
  const int r0row = tid >> 2;
  const int col8  = (tid & 3) * 8;
  const unsigned short* a0 = A  + (size_t)r0row * 2048 + col8;
  const unsigned short* a1 = A  + (size_t)(r0row + 64) * 2048 + col8;
  const unsigned short* b0 = Bm + (size_t)r0row * 2048 + col8;
  const unsigned short* b1 = Bm + (size_t)(r0row + 64) * 2048 + col8;
  char* sAc = (char*)sA + wave * 1024;   // wave-uniform LDS base, +lane*16 by HW
  char* sBc = (char*)sB + wave * 1024;

  // fragment read pointers: lane holds row (lane&15), k = (lane>>4)*8..+8
  const unsigned short* fa = sA + (size_t)(wm + (lane & 15)) * 32 + (lane >> 4) * 8;
  const unsigned short* fb = sB + (size_t)(wn + (lane & 15)) * 32 + (lane >> 4) * 8;

  for (int k0 = 0; k0 < 2048; k0 += 32) {
    gload16(a0 + k0, sAc);
    gload16(a1 + k0, sAc + 4096);
    gload16(b0 + k0, sBc);
    gload16(b1 + k0, sBc + 4096);
    __syncthreads();   // drains vmcnt: staged tile visible
    bf16x8 af[4], bq[4];
#pragma unroll
    for (int i = 0; i < 4; ++i) af[i] = *(const bf16x8*)(fa + i * 16 * 32);
#pragma unroll
    for (int i = 0; i < 4; ++i) bq[i] = *(const bf16x8*)(fb + i * 16 * 32);
#pragma unroll
    for (int mi = 0; mi < 4; ++mi)
#pragma unroll
      for (int ni = 0; ni < 4; ++ni)
        acc[mi][ni] = __builtin_amdgcn_mfma_f32_16x16x32_bf16(af[mi], bq[ni], acc[mi][ni], 0, 0, 0);
    __syncthreads();   // all reads done before next stage overwrites
  }
}

// ---------------- kernel 2: fused gates GEMM ----------------
// gates[m,n] = x@w_ih.T + hx@w_hh.T + b_ih + b_hh  (all n)
//            + cx@w_pi.T (n<2048) / cx@w_pf.T (2048<=n<4096)
__global__ void __launch_bounds__(256) gemm_gates(const unsigned short* __restrict__ bf,
                                                  const float* __restrict__ bih,
                                                  const float* __restrict__ bhh,
                                                  float* __restrict__ gates) {
  __shared__ __align__(16) unsigned short sA[128 * 32];
  __shared__ __align__(16) unsigned short sB[128 * 32];
  const int nb = blockIdx.x;          // 0..63
  const int mb = blockIdx.y;          // 0..31
  const int n0 = nb * 128, m0 = mb * 128;

  f32x4 acc[4][4];
#pragma unroll
  for (int i = 0; i < 4; ++i)
#pragma unroll
    for (int j = 0; j < 4; ++j) acc[i][j] = (f32x4){0.f, 0.f, 0.f, 0.f};

  const unsigned short* xb  = bf + O_X  + (size_t)m0 * 2048;
  const unsigned short* hxb = bf + O_HX + (size_t)m0 * 2048;
  kseg2048(xb,  bf + O_WIH + (size_t)n0 * 2048, sA, sB, acc);
  kseg2048(hxb, bf + O_WHH + (size_t)n0 * 2048, sA, sB, acc);
  if (n0 < 4096) {  // peephole segment on i/f gate columns (block-uniform branch)
    const unsigned short* w3 = (n0 < 2048)
        ? (bf + O_WPI + (size_t)n0 * 2048)
        : (bf + O_WPF + (size_t)(n0 - 2048) * 2048);
    kseg2048(bf + O_CX + (size_t)m0 * 2048, w3, sA, sB, acc);
  }

  // epilogue: C/D frag layout col=lane&15, row=(lane>>4)*4+reg  [m89-verified]
  const int lane = threadIdx.x & 63;
  const int wave = threadIdx.x >> 6;
  const int wm = (wave >> 1) * 64, wn = (wave & 1) * 64;
  const int col0 = n0 + wn + (lane & 15);
  const int row0 = m0 + wm + ((lane >> 4) << 2);
#pragma unroll
  for (int ni = 0; ni < 4; ++ni) {
    const int col = col0 + ni * 16;
    const float bias = bih[col] + bhh[col];
#pragma unroll
    for (int mi = 0; mi < 4; ++mi) {
#pragma unroll
      for (int r = 0; r < 4; ++r) {
        const int row = row0 + mi * 16 + r;
        gates[(size_t)row * NGATE + col] = acc[mi][ni][r] + bias;
      }
    }
  }
}

// ---------------- kernel 3: elementwise cy ----------------
__global__ void e1_kernel(const float* __restrict__ gates, const float* __restrict__ cx,
                          const float* __restrict__ td0, const float* __restrict__ td1,
                          const float* __restrict__ pa, const float* __restrict__ pb,
                          float* __restrict__ cy_out, unsigned short* __restrict__ cy_bf) {
  const float A  = pa[0];
  const float Bc = pb[0];
  const int total = (BB * OUT_D) / 4;   // float4 chunks
  for (int c = blockIdx.x * blockDim.x + threadIdx.x; c < total;
       c += gridDim.x * blockDim.x) {
    const int m = c >> 9;               // 512 chunks per row
    const int n = (c & 511) * 4;
    const float* gp = gates + (size_t)m * NGATE + n;
    float4 gi  = *(const float4*)(gp);
    float4 gf  = *(const float4*)(gp + 2048);
    float4 gg  = *(const float4*)(gp + 4096);
    float4 cxv = *(const float4*)(cx + (size_t)m * OUT_D + n);
    const float fc = A * __expf(-Bc * td0[m]);   // forcoff -> f gate
    const float ic = A * __expf(-Bc * td1[m]);   // incoff  -> i gate
    float4 cy;
    cy.x = fc * sigm(gf.x) * cxv.x + ic * sigm(gi.x) * tanh_(gg.x);
    cy.y = fc * sigm(gf.y) * cxv.y + ic * sigm(gi.y) * tanh_(gg.y);
    cy.z = fc * sigm(gf.z) * cxv.z + ic * sigm(gi.z) * tanh_(gg.z);
    cy.w = fc * sigm(gf.w) * cxv.w + ic * sigm(gi.w) * tanh_(gg.w);
    *(float4*)(cy_out + (size_t)m * OUT_D + n) = cy;
    ushort4 cb;
    cb.x = f2bf(cy.x); cb.y = f2bf(cy.y); cb.z = f2bf(cy.z); cb.w = f2bf(cy.w);
    *(ushort4*)(cy_bf + (size_t)m * OUT_D + n) = cb;
  }
}

// ---------------- kernel 4: o-gate GEMM + final elementwise ----------------
// hy[m,n] = sigm(o_pre[m,n] + cy@w_po.T) * tanh(cy[m,n])
__global__ void __launch_bounds__(256) gemm_out(const unsigned short* __restrict__ bf,
                                                const float* __restrict__ gates,
                                                const float* __restrict__ cyf,
                                                float* __restrict__ hy) {
  __shared__ __align__(16) unsigned short sA[128 * 32];
  __shared__ __align__(16) unsigned short sB[128 * 32];
  const int nb = blockIdx.x;          // 0..15
  const int mb = blockIdx.y;          // 0..31
  const int n0 = nb * 128, m0 = mb * 128;

  f32x4 acc[4][4];
#pragma unroll
  for (int i = 0; i < 4; ++i)
#pragma unroll
    for (int j = 0; j < 4; ++j) acc[i][j] = (f32x4){0.f, 0.f, 0.f, 0.f};

  // cy_bf16 lives in the (dead) cx_bf region
  kseg2048(bf + O_CX + (size_t)m0 * 2048, bf + O_WPO + (size_t)n0 * 2048, sA, sB, acc);

  const int lane = threadIdx.x & 63;
  const int wave = threadIdx.x >> 6;
  const int wm = (wave >> 1) * 64, wn = (wave & 1) * 64;
  const int col0 = n0 + wn + (lane & 15);
  const int row0 = m0 + wm + ((lane >> 4) << 2);
#pragma unroll
  for (int ni = 0; ni < 4; ++ni) {
    const int col = col0 + ni * 16;
#pragma unroll
    for (int mi = 0; mi < 4; ++mi) {
#pragma unroll
      for (int r = 0; r < 4; ++r) {
        const int row = row0 + mi * 16 + r;
        const float opre = gates[(size_t)row * NGATE + 6144 + col];
        const float o = sigm(acc[mi][ni][r] + opre);
        hy[(size_t)row * OUT_D + col] = o * tanh_(cyf[(size_t)row * OUT_D + col]);
      }
    }
  }
}

// ---------------- launch ----------------
extern "C" void kernel_launch(void* const* d_in, const int* in_sizes, int n_in,
                              void* d_out, int out_size, void* d_ws, size_t ws_size,
                              hipStream_t stream) {
  const float* x   = (const float*)d_in[0];
  const float* td0 = (const float*)d_in[1];
  const float* td1 = (const float*)d_in[2];
  const float* hx  = (const float*)d_in[3];
  const float* cx  = (const float*)d_in[4];
  const float* wih = (const float*)d_in[5];
  const float* whh = (const float*)d_in[6];
  const float* wpi = (const float*)d_in[7];
  const float* wpf = (const float*)d_in[8];
  const float* wpo = (const float*)d_in[9];
  const float* bih = (const float*)d_in[10];
  const float* bhh = (const float*)d_in[11];
  const float* pa  = (const float*)d_in[12];
  const float* pb  = (const float*)d_in[13];

  unsigned short* bf = (unsigned short*)d_ws;                 // bf16 region
  float* gates = (float*)((char*)d_ws + GATES_OFF);           // [B, 8192] fp32
  float* out = (float*)d_out;
  float* hy  = out;                                           // [B, OUT]
  float* cyf = out + (size_t)BB * OUT_D;                      // [B, OUT]

  cvt_kernel<<<dim3(2048), dim3(256), 0, stream>>>(x, hx, cx, wih, whh, wpi, wpf, wpo, bf);
  gemm_gates<<<dim3(64, 32), dim3(256), 0, stream>>>(bf, bih, bhh, gates);
  e1_kernel<<<dim3(2048), dim3(256), 0, stream>>>(gates, cx, td0, td1, pa, pb, cyf, bf + O_CX);
  gemm_out<<<dim3(16, 32), dim3(256), 0, stream>>>(bf, gates, cyf, hy);
}